// Round 12
// baseline (500.279 us; speedup 1.0000x reference)
//
#include <hip/hip_runtime.h>
#include <hip/hip_bf16.h>
#include <math.h>
#include <string.h>

#define N_NODES 50000
#define N_EDGES 800000
#define N_GRAPHS 64
#define IN_DIM 128
#define HID 64
#define HEADS 4
#define LAT 32
#define SCAN_BLOCKS ((N_NODES + 255) / 256)   // 196
#define ES_CAP 960000                          // 800k + <=3 pad per node + slack

typedef __attribute__((ext_vector_type(8))) short bf16x8;
typedef __attribute__((ext_vector_type(4))) float floatx4;
typedef __attribute__((ext_vector_type(2))) float f32x2;

__device__ inline unsigned short f2bf(float f) {   // RNE (scalar, prep only)
    unsigned u = __float_as_uint(f);
    return (unsigned short)((u + 0x7fffu + ((u >> 16) & 1u)) >> 16);
}

__device__ inline unsigned pkbf(float x, float y) {   // v_cvt_pk_bf16_f32
    float2 f{x, y};
    __hip_bfloat162 h = __float22bfloat162_rn(f);
    unsigned u;
    memcpy(&u, &h, sizeof(u));
    return u;
}

__device__ inline f32x2 bfpair(unsigned u) {   // packed bf16x2 -> f32x2
    f32x2 r;
    r.x = __uint_as_float(u << 16);
    r.y = __uint_as_float(u & 0xffff0000u);
    return r;
}

// full sum over each 16-lane DPP row via 4 rotational adds (VALU, no DS).
__device__ inline float rowsum16(float x) {
    x += __int_as_float(__builtin_amdgcn_mov_dpp(__float_as_int(x), 0x128, 0xf, 0xf, false));
    x += __int_as_float(__builtin_amdgcn_mov_dpp(__float_as_int(x), 0x124, 0xf, 0xf, false));
    x += __int_as_float(__builtin_amdgcn_mov_dpp(__float_as_int(x), 0x122, 0xf, 0xf, false));
    x += __int_as_float(__builtin_amdgcn_mov_dpp(__float_as_int(x), 0x121, 0xf, 0xf, false));
    return x;
}

// ---------------------------------------------------------------------------
// PREP (1 dispatch): conv + weight pack + zero cnt/pooled/done/es.
// Weight pack col mapping (8-tile interleave): frag col n of tile T
// (tt = T&15, half = tt>>3, i = tt&7) -> actual col half*128 + n*8 + i.
// ---------------------------------------------------------------------------
__global__ __launch_bounds__(256) void prep_kernel(
    const float* __restrict__ x, unsigned* __restrict__ xbf,
    const float* __restrict__ Wl0, const float* __restrict__ Wr0,
    const float* __restrict__ Wl1, const float* __restrict__ Wr1,
    const float* __restrict__ Wl2, const float* __restrict__ Wr2,
    unsigned short* __restrict__ B0, unsigned short* __restrict__ B1,
    unsigned short* __restrict__ B2,
    int* __restrict__ cnt, float* __restrict__ pooled, int* __restrict__ done,
    uint4* __restrict__ es4) {
    int b = blockIdx.x, t = threadIdx.x;
    if (b < 3072) {
        for (int i = b * 256 + t; i < N_NODES * IN_DIM / 2; i += 3072 * 256) {
            float2 v = reinterpret_cast<const float2*>(x)[i];
            xbf[i] = pkbf(v.x, v.y);
        }
    } else if (b < 3584) {
        int idx = (b - 3072) * 256 + t;   // 0 .. 131071
        const float *Wl, *Wr;
        unsigned short* B;
        int KC, local;
        if (idx < 65536)      { Wl = Wl0; Wr = Wr0; B = B0; KC = 4; local = idx; }
        else if (idx < 98304) { Wl = Wl1; Wr = Wr1; B = B1; KC = 2; local = idx - 65536; }
        else                  { Wl = Wl2; Wr = Wr2; B = B2; KC = 2; local = idx - 98304; }
        int j = local & 7;
        int lane = (local >> 3) & 63;
        int rem = local >> 9;
        int kc = rem % KC;
        int tile = rem / KC;
        int k = kc * 32 + (lane >> 4) * 8 + j;
        int tt = tile & 15;
        int n = (tt >> 3) * 128 + (lane & 15) * 8 + (tt & 7);   // 8-tile interleave
        const float* W = (tile < 16) ? Wl : Wr;
        B[local] = f2bf(W[k * 256 + n]);
    } else if (b < 3840) {
        int idx = (b - 3584) * 256 + t;   // 0 .. 65535
        if (idx < N_NODES) cnt[idx] = 0;
        if (idx < N_GRAPHS * HID) pooled[idx] = 0.f;
        if (idx == 0) *done = 0;
    } else {
        int idx = (b - 3840) * 256 + t;   // 0 .. 65535
        for (int i = idx; i < ES_CAP / 4; i += 65536)
            es4[i] = uint4{0, 0, 0, 0};
    }
}

// ---------------------------------------------------------------------------
// Degree histogram
// ---------------------------------------------------------------------------
__global__ __launch_bounds__(256) void deg_kernel(const int* __restrict__ dsts,
                                                  int* __restrict__ cnt, int E) {
    int e = blockIdx.x * 256 + threadIdx.x;
    if (e < E) atomicAdd(&cnt[dsts[e]], 1);
}

// ---------------------------------------------------------------------------
// Single-kernel exclusive scan of x4-padded degrees, decoupled lookback.
// ---------------------------------------------------------------------------
__global__ __launch_bounds__(256) void scan_kernel(const int* __restrict__ cnt,
                                                   int* __restrict__ offs,
                                                   int* __restrict__ sc,
                                                   int* __restrict__ agg) {
    __shared__ int buf[256];
    int b = blockIdx.x, t = threadIdx.x;
    int i = b * 256 + t;
    int v = (i < N_NODES) ? ((cnt[i] + 3) & ~3) : 0;
    buf[t] = v;
    __syncthreads();
    #pragma unroll
    for (int off = 1; off < 256; off <<= 1) {
        int tmp = (t >= off) ? buf[t - off] : 0;
        __syncthreads();
        buf[t] += tmp;
        __syncthreads();
    }
    int incl = buf[t];
    if (t == 255)
        __hip_atomic_store(&agg[b], buf[255] | 0x40000000,
                           __ATOMIC_RELEASE, __HIP_MEMORY_SCOPE_AGENT);
    int contrib = 0;
    if (t < b) {   // b <= 195 < 256: one predecessor per thread
        int vv;
        do {
            vv = __hip_atomic_load(&agg[t], __ATOMIC_ACQUIRE, __HIP_MEMORY_SCOPE_AGENT);
        } while (vv < 0 || !(vv & 0x40000000));
        contrib = vv & 0x3FFFFFFF;
    }
    __syncthreads();
    buf[t] = contrib;
    __syncthreads();
    for (int off = 128; off; off >>= 1) {
        if (t < off) buf[t] += buf[t + off];
        __syncthreads();
    }
    if (i < N_NODES) {
        offs[i] = buf[0] + incl - v;   // exclusive, 16B-aligned
        sc[i] = 0;
    }
}

__global__ __launch_bounds__(256) void scatter_kernel(const int* __restrict__ srcs,
                                                      const int* __restrict__ dsts,
                                                      const int* __restrict__ offs,
                                                      int* __restrict__ sc,
                                                      int* __restrict__ es, int E) {
    int e = blockIdx.x * 256 + threadIdx.x;
    if (e < E) {
        int d = dsts[e];
        int pos = offs[d] + atomicAdd(&sc[d], 1);
        es[pos] = srcs[e];
    }
}

// ---------------------------------------------------------------------------
// MFMA GEMM v2: 32 rows x 512 cols per block, NO LDS.
// Each wave: 2 row-tiles x 8 col-tiles; A-frags loaded direct from global
// (L2/L3-resident); each B-frag load feeds 2 MFMAs; epilogue uses
// v_cvt_pk_bf16_f32 and 8 dwordx4 stores/lane (8-tile col interleave).
// ---------------------------------------------------------------------------
template <int K>
__global__ __launch_bounds__(256) void gemm_mfma_kernel(
    const unsigned short* __restrict__ Abf,
    const unsigned short* __restrict__ Bpk,
    unsigned* __restrict__ xlp_u,
    unsigned* __restrict__ xrp_u) {
    constexpr int KC = K / 32;
    int br = blockIdx.x * 32;
    int t = threadIdx.x;
    int wave = t >> 6, lane = t & 63;
    int quad = lane >> 4, l16 = lane & 15;

    // A fragments for both row-tiles: lane (quad,l16) needs
    // A[row = base+l16][k = kc*32 + quad*8 .. +8]
    bf16x8 afrag[2][KC];
    #pragma unroll
    for (int rt = 0; rt < 2; ++rt) {
        int row = br + rt * 16 + l16;
        if (row > N_NODES - 1) row = N_NODES - 1;   // clamp (stores guarded)
        const unsigned short* ap = Abf + (size_t)row * K + quad * 8;
        #pragma unroll
        for (int kc = 0; kc < KC; ++kc)
            afrag[rt][kc] = *reinterpret_cast<const bf16x8*>(ap + kc * 32);
    }

    floatx4 acc[2][8];
    #pragma unroll
    for (int rt = 0; rt < 2; ++rt)
        #pragma unroll
        for (int i = 0; i < 8; ++i) acc[rt][i] = floatx4{0.f, 0.f, 0.f, 0.f};

    const bf16x8* bbase = reinterpret_cast<const bf16x8*>(Bpk)
                          + (size_t)(wave * 8) * KC * 64 + lane;
    #pragma unroll
    for (int i = 0; i < 8; ++i) {
        #pragma unroll
        for (int kc = 0; kc < KC; ++kc) {
            bf16x8 bfr = bbase[(i * KC + kc) * 64];
            acc[0][i] = __builtin_amdgcn_mfma_f32_16x16x32_bf16(afrag[0][kc], bfr, acc[0][i], 0, 0, 0);
            acc[1][i] = __builtin_amdgcn_mfma_f32_16x16x32_bf16(afrag[1][kc], bfr, acc[1][i], 0, 0, 0);
        }
    }

    // C/D: row = quad*4 + r, frag col = l16. Tile i holds actual col
    // (wave&1)*128 + l16*8 + i -> lane's 8 tiles = 8 adjacent cols.
    unsigned* dst = (wave < 2) ? xlp_u : xrp_u;
    int cbase = (wave & 1) * 64 + l16 * 4;   // dword col
    #pragma unroll
    for (int rt = 0; rt < 2; ++rt) {
        if (br + rt * 16 >= N_NODES) break;
        #pragma unroll
        for (int r = 0; r < 4; ++r) {
            int row = br + rt * 16 + quad * 4 + r;
            uint4 pk;
            pk.x = pkbf(acc[rt][0][r], acc[rt][1][r]);
            pk.y = pkbf(acc[rt][2][r], acc[rt][3][r]);
            pk.z = pkbf(acc[rt][4][r], acc[rt][5][r]);
            pk.w = pkbf(acc[rt][6][r], acc[rt][7][r]);
            *reinterpret_cast<uint4*>(&dst[(size_t)row * 128 + cbase]) = pk;
        }
    }
}

// ---------------------------------------------------------------------------
// Attention (R8 body — best measured): ONE 64-lane wave per node.
// lane = h*16 + dq; int4 uniform broadcast of 4 edge indices; DPP rowsum;
// no-max softmax; zero DS in edge loop.
// ---------------------------------------------------------------------------
__global__ __launch_bounds__(256) void attn_kernel(const unsigned* __restrict__ xlp,
                                                   const unsigned* __restrict__ xrp,
                                                   const int* __restrict__ es,
                                                   const int* __restrict__ offs,
                                                   const int* __restrict__ deg,
                                                   const float4* __restrict__ att4,
                                                   const float4* __restrict__ bias4,
                                                   float* __restrict__ hout,
                                                   unsigned* __restrict__ hbf) {
    int node = blockIdx.x * 4 + (threadIdx.x >> 6);
    int lane = threadIdx.x & 63;
    int beg = offs[node];
    int end = beg + deg[node];
    uint2 xr2 = reinterpret_cast<const uint2*>(xrp)[(size_t)node * 64 + lane];
    f32x2 xrA = bfpair(xr2.x), xrB = bfpair(xr2.y);
    float4 at_t = att4[lane];
    f32x2 atA = {at_t.x, at_t.y}, atB = {at_t.z, at_t.w};
    const char* xbase = (const char*)xlp;
    int laneoff = lane << 3;

    float l = 0.f;
    f32x2 accA = {0.f, 0.f}, accB = {0.f, 0.f};

    auto edge_z = [&](uint2 v, f32x2& xa, f32x2& xb) -> float {
        xa = bfpair(v.x);
        xb = bfpair(v.y);
        f32x2 ea = xa + xrA;
        f32x2 eb = xb + xrB;
        ea = __builtin_elementwise_max(ea, ea * 0.2f);
        eb = __builtin_elementwise_max(eb, eb * 0.2f);
        f32x2 zz = ea * atA;
        zz += eb * atB;
        return zz.x + zz.y;
    };
    auto gather = [&](int s) -> uint2 {
        return *reinterpret_cast<const uint2*>(
            xbase + (((size_t)(unsigned)s) << 9) + laneoff);
    };

    for (int cb = beg; cb < end; cb += 4) {
        int4 s4 = *reinterpret_cast<const int4*>(&es[cb]);   // uniform broadcast
        uint2 v0 = gather(s4.x);
        uint2 v1 = gather(s4.y);
        uint2 v2 = gather(s4.z);
        uint2 v3 = gather(s4.w);
        f32x2 xa0, xb0, xa1, xb1, xa2, xb2, xa3, xb3;
        float z0 = rowsum16(edge_z(v0, xa0, xb0));
        float z1 = rowsum16(edge_z(v1, xa1, xb1));
        float z2 = rowsum16(edge_z(v2, xa2, xb2));
        float z3 = rowsum16(edge_z(v3, xa3, xb3));
        float p0 = __expf(z0);                               // cb+0 < end always
        float p1 = (cb + 1 < end) ? __expf(z1) : 0.f;
        float p2 = (cb + 2 < end) ? __expf(z2) : 0.f;
        float p3 = (cb + 3 < end) ? __expf(z3) : 0.f;
        accA += p0 * xa0 + p1 * xa1 + p2 * xa2 + p3 * xa3;
        accB += p0 * xb0 + p1 * xb1 + p2 * xb2 + p3 * xb3;
        l += (p0 + p1) + (p2 + p3);
    }

    float inv = 1.f / (l + 1e-16f);
    float a0 = accA.x * inv, a1 = accA.y * inv;
    float a2 = accB.x * inv, a3 = accB.y * inv;
    a0 += __shfl_xor(a0, 16); a0 += __shfl_xor(a0, 32);
    a1 += __shfl_xor(a1, 16); a1 += __shfl_xor(a1, 32);
    a2 += __shfl_xor(a2, 16); a2 += __shfl_xor(a2, 32);
    a3 += __shfl_xor(a3, 16); a3 += __shfl_xor(a3, 32);
    if (lane < 16) {
        float4 bv = bias4[lane];
        float4 o;
        o.x = 0.25f * a0 + bv.x; o.x = (o.x > 0.f) ? o.x : 0.1f * o.x;
        o.y = 0.25f * a1 + bv.y; o.y = (o.y > 0.f) ? o.y : 0.1f * o.y;
        o.z = 0.25f * a2 + bv.z; o.z = (o.z > 0.f) ? o.z : 0.1f * o.z;
        o.w = 0.25f * a3 + bv.w; o.w = (o.w > 0.f) ? o.w : 0.1f * o.w;
        if (hout)
            *reinterpret_cast<float4*>(&hout[(size_t)node * HID + lane * 4]) = o;
        if (hbf) {
            uint2 pk;
            pk.x = pkbf(o.x, o.y);
            pk.y = pkbf(o.z, o.w);
            *reinterpret_cast<uint2*>(&hbf[(size_t)node * 32 + lane * 2]) = pk;
        }
    }
}

// ---------------------------------------------------------------------------
// Pool + BN + FC fused: 196 blocks pool (sorted-run atomics); last block
// (device atomic counter) performs BN over graphs + FC.
// ---------------------------------------------------------------------------
__global__ __launch_bounds__(256) void pool_final_kernel(
    const float* __restrict__ hfin, const int* __restrict__ batch,
    float* __restrict__ pooled,
    const float* __restrict__ gamma, const float* __restrict__ beta,
    const float* __restrict__ fcW, const float* __restrict__ fcb,
    float* __restrict__ out, int* __restrict__ done) {
    int base = blockIdx.x * 256;
    int g = threadIdx.x >> 6, lane = threadIdx.x & 63;
    int lim = min(base + 256, N_NODES);
    int cur = -1;
    float s = 0.f;
    for (int i = base + g; i < lim; i += 4) {
        int b = batch[i];
        if (b != cur) {
            if (cur >= 0) atomicAdd(&pooled[cur * HID + lane], s);
            cur = b; s = 0.f;
        }
        s += hfin[(size_t)i * HID + lane];
    }
    if (cur >= 0) atomicAdd(&pooled[cur * HID + lane], s);

    __threadfence();
    __syncthreads();
    __shared__ int lastS;
    if (threadIdx.x == 0)
        lastS = (atomicAdd(done, 1) == (int)gridDim.x - 1);
    __syncthreads();
    if (!lastS) return;

    // ---- final phase (single block) ----
    __shared__ float P[N_GRAPHS * HID];
    __shared__ float normS[N_GRAPHS * HID];
    __shared__ float meanS[HID], rstdS[HID];
    int t = threadIdx.x;
    for (int i = t; i < N_GRAPHS * HID; i += 256)
        P[i] = __hip_atomic_load(&pooled[i], __ATOMIC_RELAXED, __HIP_MEMORY_SCOPE_AGENT);
    __syncthreads();
    if (t < HID) {
        float s2 = 0.f;
        for (int g2 = 0; g2 < N_GRAPHS; ++g2) s2 += P[g2 * HID + t];
        float mean = s2 / (float)N_GRAPHS;
        float v = 0.f;
        for (int g2 = 0; g2 < N_GRAPHS; ++g2) {
            float dd = P[g2 * HID + t] - mean;
            v += dd * dd;
        }
        v /= (float)N_GRAPHS;
        meanS[t] = mean;
        rstdS[t] = rsqrtf(v + 1e-5f);
    }
    __syncthreads();
    for (int i = t; i < N_GRAPHS * HID; i += 256) {
        int d = i & 63;
        normS[i] = (P[i] - meanS[d]) * rstdS[d] * gamma[d] + beta[d];
    }
    __syncthreads();
    for (int i = t; i < N_GRAPHS * LAT; i += 256) {
        int g2 = i >> 5, lat = i & 31;
        float s2 = fcb[lat];
        for (int d = 0; d < HID; ++d) s2 += normS[g2 * HID + d] * fcW[lat * HID + d];
        out[i] = s2;
    }
}

// ---------------------------------------------------------------------------
extern "C" void kernel_launch(void* const* d_in, const int* in_sizes, int n_in,
                              void* d_out, int out_size, void* d_ws, size_t ws_size,
                              hipStream_t stream) {
    const float* x      = (const float*)d_in[0];
    const int*   ei     = (const int*)d_in[1];
    const int*   batch  = (const int*)d_in[2];
    const float* Wl[3]  = {(const float*)d_in[3], (const float*)d_in[7],  (const float*)d_in[11]};
    const float* Wr[3]  = {(const float*)d_in[4], (const float*)d_in[8],  (const float*)d_in[12]};
    const float* att[3] = {(const float*)d_in[5], (const float*)d_in[9],  (const float*)d_in[13]};
    const float* bia[3] = {(const float*)d_in[6], (const float*)d_in[10], (const float*)d_in[14]};
    const float* gamma  = (const float*)d_in[15];
    const float* beta   = (const float*)d_in[16];
    const float* fcW    = (const float*)d_in[17];
    const float* fcb    = (const float*)d_in[18];
    float* out = (float*)d_out;

    char* p = (char*)d_ws;
    auto alloc = [&](size_t bytes) {
        char* r = p;
        p += (bytes + 255) & ~(size_t)255;
        return r;
    };
    unsigned* xbf   = (unsigned*)alloc((size_t)N_NODES * IN_DIM * 2);   // bf16 x; reused as hfin
    unsigned* xlp   = (unsigned*)alloc((size_t)N_NODES * 256 * 2);
    unsigned* xrp   = (unsigned*)alloc((size_t)N_NODES * 256 * 2);
    unsigned* hbf0  = (unsigned*)alloc((size_t)N_NODES * HID * 2);
    unsigned* hbf1  = (unsigned*)alloc((size_t)N_NODES * HID * 2);
    unsigned short* Bpk0 = (unsigned short*)alloc(32 * 4 * 512 * 2);
    unsigned short* Bpk1 = (unsigned short*)alloc(32 * 2 * 512 * 2);
    unsigned short* Bpk2 = (unsigned short*)alloc(32 * 2 * 512 * 2);
    int*   es      = (int*)alloc((size_t)ES_CAP * 4);
    int*   offs    = (int*)alloc((size_t)N_NODES * 4);
    int*   cnt     = (int*)alloc((size_t)N_NODES * 4);   // true degrees
    int*   sc      = (int*)alloc((size_t)N_NODES * 4);   // scatter cursors
    int*   agg     = (int*)alloc((size_t)SCAN_BLOCKS * 4);
    int*   done    = (int*)alloc(256);
    float* pooled  = (float*)alloc((size_t)N_GRAPHS * HID * 4);
    float* hfin    = (float*)xbf;   // alias: xbf dead after layer-0 GEMM

    const int* srcs = ei;
    const int* dsts = ei + N_EDGES;

    // 1: prep (conv + pack + zeros)
    prep_kernel<<<4096, 256, 0, stream>>>(x, xbf, Wl[0], Wr[0], Wl[1], Wr[1],
                                          Wl[2], Wr[2], Bpk0, Bpk1, Bpk2,
                                          cnt, pooled, done, (uint4*)es);
    // 2-4: counting sort (deg -> lookback scan -> scatter)
    int eb = (N_EDGES + 255) / 256;
    deg_kernel<<<eb, 256, 0, stream>>>(dsts, cnt, N_EDGES);
    scan_kernel<<<SCAN_BLOCKS, 256, 0, stream>>>(cnt, offs, sc, agg);
    scatter_kernel<<<eb, 256, 0, stream>>>(srcs, dsts, offs, sc, es, N_EDGES);

    // 5-10: 3 GATv2 layers
    int gb = (N_NODES + 31) / 32;   // 1563
    gemm_mfma_kernel<IN_DIM><<<gb, 256, 0, stream>>>((const unsigned short*)xbf, Bpk0, xlp, xrp);
    attn_kernel<<<N_NODES / 4, 256, 0, stream>>>(xlp, xrp, es, offs, cnt,
                                                 (const float4*)att[0],
                                                 (const float4*)bia[0], nullptr, hbf0);
    gemm_mfma_kernel<HID><<<gb, 256, 0, stream>>>((const unsigned short*)hbf0, Bpk1, xlp, xrp);
    attn_kernel<<<N_NODES / 4, 256, 0, stream>>>(xlp, xrp, es, offs, cnt,
                                                 (const float4*)att[1],
                                                 (const float4*)bia[1], nullptr, hbf1);
    gemm_mfma_kernel<HID><<<gb, 256, 0, stream>>>((const unsigned short*)hbf1, Bpk2, xlp, xrp);
    attn_kernel<<<N_NODES / 4, 256, 0, stream>>>(xlp, xrp, es, offs, cnt,
                                                 (const float4*)att[2],
                                                 (const float4*)bia[2], hfin, nullptr);

    // 11: pool + BN + FC (last-block-done)
    pool_final_kernel<<<SCAN_BLOCKS, 256, 0, stream>>>(hfin, batch, pooled,
                                                       gamma, beta, fcW, fcb,
                                                       out, done);
}

// Round 13
// 486.902 us; speedup vs baseline: 1.0275x; 1.0275x over previous
//
#include <hip/hip_runtime.h>
#include <hip/hip_bf16.h>
#include <math.h>
#include <string.h>

#define N_NODES 50000
#define N_EDGES 800000
#define N_GRAPHS 64
#define IN_DIM 128
#define HID 64
#define HEADS 4
#define LAT 32
#define SCAN_BLOCKS ((N_NODES + 255) / 256)   // 196
#define ES_CAP 960000                          // 800k + <=3 pad per node + slack

typedef __attribute__((ext_vector_type(8))) short bf16x8;
typedef __attribute__((ext_vector_type(4))) float floatx4;
typedef __attribute__((ext_vector_type(2))) float f32x2;

__device__ inline unsigned short f2bf(float f) {   // RNE (scalar, prep only)
    unsigned u = __float_as_uint(f);
    return (unsigned short)((u + 0x7fffu + ((u >> 16) & 1u)) >> 16);
}

__device__ inline unsigned pkbf(float x, float y) {   // v_cvt_pk_bf16_f32
    float2 f{x, y};
    __hip_bfloat162 h = __float22bfloat162_rn(f);
    unsigned u;
    memcpy(&u, &h, sizeof(u));
    return u;
}

__device__ inline f32x2 bfpair(unsigned u) {   // packed bf16x2 -> f32x2
    f32x2 r;
    r.x = __uint_as_float(u << 16);
    r.y = __uint_as_float(u & 0xffff0000u);
    return r;
}

// full sum over each 16-lane DPP row via 4 rotational adds (VALU, no DS).
__device__ inline float rowsum16(float x) {
    x += __int_as_float(__builtin_amdgcn_mov_dpp(__float_as_int(x), 0x128, 0xf, 0xf, false));
    x += __int_as_float(__builtin_amdgcn_mov_dpp(__float_as_int(x), 0x124, 0xf, 0xf, false));
    x += __int_as_float(__builtin_amdgcn_mov_dpp(__float_as_int(x), 0x122, 0xf, 0xf, false));
    x += __int_as_float(__builtin_amdgcn_mov_dpp(__float_as_int(x), 0x121, 0xf, 0xf, false));
    return x;
}

// ---------------------------------------------------------------------------
// PREP (1 dispatch): conv + weight pack + zero cnt/pooled/done/es.
// Weight pack col mapping (4-tile interleave): frag col n of tile T
// (tt = T&15) -> actual col (tt>>2)*64 + n*4 + (tt&3), so a lane's 4 tile
// accs are 4 adjacent columns -> one dwordx2 store of 4 bf16.
// ---------------------------------------------------------------------------
__global__ __launch_bounds__(256) void prep_kernel(
    const float* __restrict__ x, unsigned* __restrict__ xbf,
    const float* __restrict__ Wl0, const float* __restrict__ Wr0,
    const float* __restrict__ Wl1, const float* __restrict__ Wr1,
    const float* __restrict__ Wl2, const float* __restrict__ Wr2,
    unsigned short* __restrict__ B0, unsigned short* __restrict__ B1,
    unsigned short* __restrict__ B2,
    int* __restrict__ cnt, float* __restrict__ pooled, int* __restrict__ done,
    uint4* __restrict__ es4) {
    int b = blockIdx.x, t = threadIdx.x;
    if (b < 3072) {
        for (int i = b * 256 + t; i < N_NODES * IN_DIM / 2; i += 3072 * 256) {
            float2 v = reinterpret_cast<const float2*>(x)[i];
            xbf[i] = pkbf(v.x, v.y);
        }
    } else if (b < 3584) {
        int idx = (b - 3072) * 256 + t;   // 0 .. 131071
        const float *Wl, *Wr;
        unsigned short* B;
        int KC, local;
        if (idx < 65536)      { Wl = Wl0; Wr = Wr0; B = B0; KC = 4; local = idx; }
        else if (idx < 98304) { Wl = Wl1; Wr = Wr1; B = B1; KC = 2; local = idx - 65536; }
        else                  { Wl = Wl2; Wr = Wr2; B = B2; KC = 2; local = idx - 98304; }
        int j = local & 7;
        int lane = (local >> 3) & 63;
        int rem = local >> 9;
        int kc = rem % KC;
        int tile = rem / KC;
        int k = kc * 32 + (lane >> 4) * 8 + j;
        int tt = tile & 15;
        int n = (tt >> 2) * 64 + (lane & 15) * 4 + (tt & 3);   // 4-tile interleave
        const float* W = (tile < 16) ? Wl : Wr;
        B[local] = f2bf(W[k * 256 + n]);
    } else if (b < 3840) {
        int idx = (b - 3584) * 256 + t;   // 0 .. 65535
        if (idx < N_NODES) cnt[idx] = 0;
        if (idx < N_GRAPHS * HID) pooled[idx] = 0.f;
        if (idx == 0) *done = 0;
    } else {
        int idx = (b - 3840) * 256 + t;   // 0 .. 65535
        for (int i = idx; i < ES_CAP / 4; i += 65536)
            es4[i] = uint4{0, 0, 0, 0};
    }
}

// ---------------------------------------------------------------------------
// Degree histogram, 4 edges/thread (int4)
// ---------------------------------------------------------------------------
__global__ __launch_bounds__(256) void deg_kernel(const int4* __restrict__ dsts4,
                                                  int* __restrict__ cnt, int E4) {
    int i = blockIdx.x * 256 + threadIdx.x;
    if (i < E4) {
        int4 d = dsts4[i];
        atomicAdd(&cnt[d.x], 1);
        atomicAdd(&cnt[d.y], 1);
        atomicAdd(&cnt[d.z], 1);
        atomicAdd(&cnt[d.w], 1);
    }
}

// ---------------------------------------------------------------------------
// Single-kernel exclusive scan of x4-padded degrees, decoupled lookback.
// ---------------------------------------------------------------------------
__global__ __launch_bounds__(256) void scan_kernel(const int* __restrict__ cnt,
                                                   int* __restrict__ offs,
                                                   int* __restrict__ sc,
                                                   int* __restrict__ agg) {
    __shared__ int buf[256];
    int b = blockIdx.x, t = threadIdx.x;
    int i = b * 256 + t;
    int v = (i < N_NODES) ? ((cnt[i] + 3) & ~3) : 0;
    buf[t] = v;
    __syncthreads();
    #pragma unroll
    for (int off = 1; off < 256; off <<= 1) {
        int tmp = (t >= off) ? buf[t - off] : 0;
        __syncthreads();
        buf[t] += tmp;
        __syncthreads();
    }
    int incl = buf[t];
    if (t == 255)
        __hip_atomic_store(&agg[b], buf[255] | 0x40000000,
                           __ATOMIC_RELEASE, __HIP_MEMORY_SCOPE_AGENT);
    int contrib = 0;
    if (t < b) {   // b <= 195 < 256: one predecessor per thread
        int vv;
        do {
            vv = __hip_atomic_load(&agg[t], __ATOMIC_ACQUIRE, __HIP_MEMORY_SCOPE_AGENT);
        } while (vv < 0 || !(vv & 0x40000000));
        contrib = vv & 0x3FFFFFFF;
    }
    __syncthreads();
    buf[t] = contrib;
    __syncthreads();
    for (int off = 128; off; off >>= 1) {
        if (t < off) buf[t] += buf[t + off];
        __syncthreads();
    }
    if (i < N_NODES) {
        offs[i] = buf[0] + incl - v;   // exclusive, 16B-aligned
        sc[i] = 0;
    }
}

// ---------------------------------------------------------------------------
// Scatter, 4 edges/thread (int4 loads of src+dst)
// ---------------------------------------------------------------------------
__global__ __launch_bounds__(256) void scatter_kernel(const int4* __restrict__ srcs4,
                                                      const int4* __restrict__ dsts4,
                                                      const int* __restrict__ offs,
                                                      int* __restrict__ sc,
                                                      int* __restrict__ es, int E4) {
    int i = blockIdx.x * 256 + threadIdx.x;
    if (i < E4) {
        int4 s = srcs4[i];
        int4 d = dsts4[i];
        es[offs[d.x] + atomicAdd(&sc[d.x], 1)] = s.x;
        es[offs[d.y] + atomicAdd(&sc[d.y], 1)] = s.y;
        es[offs[d.z] + atomicAdd(&sc[d.z], 1)] = s.z;
        es[offs[d.w] + atomicAdd(&sc[d.w], 1)] = s.w;
    }
}

// ---------------------------------------------------------------------------
// MFMA GEMM v3: 64 rows x 512 cols per block, 512 threads (8 waves).
// A staged to LDS in fragment order (conflict-free b128 ops, proven in R10).
// Wave w: half which=w>>2 (xl/xr), col-group g=w&3 -> 4 col-tiles x 4
// row-tiles. Each B-frag load feeds 4 MFMAs; afrag reused across 4 tiles.
// Epilogue: v_cvt_pk_bf16_f32 + coalesced dwordx2 stores (4-tile interleave).
// ---------------------------------------------------------------------------
template <int K>
__global__ __launch_bounds__(512) void gemm_mfma_kernel(
    const unsigned short* __restrict__ Abf,
    const unsigned short* __restrict__ Bpk,
    unsigned* __restrict__ xlp_u,
    unsigned* __restrict__ xrp_u) {
    constexpr int KC = K / 32;
    constexpr int CHUNKS = 64 * K / 8;        // 512 (K=64) or 1024 (K=128)
    __shared__ short As[CHUNKS * 8];
    int br = blockIdx.x * 64;
    int t = threadIdx.x;

    // stage: chunk c = ((rt*KC + kc)*4 + quad)*16 + l16  (lane-linear per frag)
    for (int c = t; c < CHUNKS; c += 512) {
        int rt = c / (KC * 64);
        int rem = c % (KC * 64);
        int kc = rem >> 6;
        int quad = (rem >> 4) & 3, l16 = rem & 15;
        int row = br + rt * 16 + l16;
        if (row >= N_NODES) row = N_NODES - 1;
        *reinterpret_cast<uint4*>(&As[c * 8]) =
            *reinterpret_cast<const uint4*>(&Abf[(size_t)row * K + kc * 32 + quad * 8]);
    }
    __syncthreads();

    int wave = t >> 6, lane = t & 63;
    int quad = lane >> 4, l16 = lane & 15;
    int which = wave >> 2, g = wave & 3;

    bf16x8 afrag[4][KC];
    #pragma unroll
    for (int rt = 0; rt < 4; ++rt)
        #pragma unroll
        for (int kc = 0; kc < KC; ++kc)
            afrag[rt][kc] = *reinterpret_cast<const bf16x8*>(
                &As[(((rt * KC + kc) * 4 + quad) * 16 + l16) * 8]);

    floatx4 acc[4][4];   // [rt][i]
    #pragma unroll
    for (int rt = 0; rt < 4; ++rt)
        #pragma unroll
        for (int i = 0; i < 4; ++i) acc[rt][i] = floatx4{0.f, 0.f, 0.f, 0.f};

    #pragma unroll
    for (int i = 0; i < 4; ++i) {
        int T = which * 16 + g * 4 + i;
        #pragma unroll
        for (int kc = 0; kc < KC; ++kc) {
            bf16x8 bfr = *reinterpret_cast<const bf16x8*>(
                &Bpk[(size_t)((T * KC + kc) * 64 + lane) * 8]);
            #pragma unroll
            for (int rt = 0; rt < 4; ++rt)
                acc[rt][i] = __builtin_amdgcn_mfma_f32_16x16x32_bf16(
                    afrag[rt][kc], bfr, acc[rt][i], 0, 0, 0);
        }
    }

    // C/D: row = quad*4 + r, frag col = l16; tile i -> actual col
    // g*64 + l16*4 + i  => lane's 4 accs at reg r are 4 adjacent cols.
    unsigned* dst = which ? xrp_u : xlp_u;
    int dcol = g * 32 + l16 * 2;   // dword col
    #pragma unroll
    for (int rt = 0; rt < 4; ++rt) {
        #pragma unroll
        for (int r = 0; r < 4; ++r) {
            int row = br + rt * 16 + quad * 4 + r;
            if (row >= N_NODES) continue;
            uint2 pk;
            pk.x = pkbf(acc[rt][0][r], acc[rt][1][r]);
            pk.y = pkbf(acc[rt][2][r], acc[rt][3][r]);
            *reinterpret_cast<uint2*>(&dst[(size_t)row * 128 + dcol]) = pk;
        }
    }
}

// ---------------------------------------------------------------------------
// Attention (R8 body — best measured): ONE 64-lane wave per node.
// lane = h*16 + dq; int4 uniform broadcast of 4 edge indices; DPP rowsum;
// no-max softmax; zero DS in edge loop.
// ---------------------------------------------------------------------------
__global__ __launch_bounds__(256) void attn_kernel(const unsigned* __restrict__ xlp,
                                                   const unsigned* __restrict__ xrp,
                                                   const int* __restrict__ es,
                                                   const int* __restrict__ offs,
                                                   const int* __restrict__ deg,
                                                   const float4* __restrict__ att4,
                                                   const float4* __restrict__ bias4,
                                                   float* __restrict__ hout,
                                                   unsigned* __restrict__ hbf) {
    int node = blockIdx.x * 4 + (threadIdx.x >> 6);
    int lane = threadIdx.x & 63;
    int beg = offs[node];
    int end = beg + deg[node];
    uint2 xr2 = reinterpret_cast<const uint2*>(xrp)[(size_t)node * 64 + lane];
    f32x2 xrA = bfpair(xr2.x), xrB = bfpair(xr2.y);
    float4 at_t = att4[lane];
    f32x2 atA = {at_t.x, at_t.y}, atB = {at_t.z, at_t.w};
    const char* xbase = (const char*)xlp;
    int laneoff = lane << 3;

    float l = 0.f;
    f32x2 accA = {0.f, 0.f}, accB = {0.f, 0.f};

    auto edge_z = [&](uint2 v, f32x2& xa, f32x2& xb) -> float {
        xa = bfpair(v.x);
        xb = bfpair(v.y);
        f32x2 ea = xa + xrA;
        f32x2 eb = xb + xrB;
        ea = __builtin_elementwise_max(ea, ea * 0.2f);
        eb = __builtin_elementwise_max(eb, eb * 0.2f);
        f32x2 zz = ea * atA;
        zz += eb * atB;
        return zz.x + zz.y;
    };
    auto gather = [&](int s) -> uint2 {
        return *reinterpret_cast<const uint2*>(
            xbase + (((size_t)(unsigned)s) << 9) + laneoff);
    };

    for (int cb = beg; cb < end; cb += 4) {
        int4 s4 = *reinterpret_cast<const int4*>(&es[cb]);   // uniform broadcast
        uint2 v0 = gather(s4.x);
        uint2 v1 = gather(s4.y);
        uint2 v2 = gather(s4.z);
        uint2 v3 = gather(s4.w);
        f32x2 xa0, xb0, xa1, xb1, xa2, xb2, xa3, xb3;
        float z0 = rowsum16(edge_z(v0, xa0, xb0));
        float z1 = rowsum16(edge_z(v1, xa1, xb1));
        float z2 = rowsum16(edge_z(v2, xa2, xb2));
        float z3 = rowsum16(edge_z(v3, xa3, xb3));
        float p0 = __expf(z0);                               // cb+0 < end always
        float p1 = (cb + 1 < end) ? __expf(z1) : 0.f;
        float p2 = (cb + 2 < end) ? __expf(z2) : 0.f;
        float p3 = (cb + 3 < end) ? __expf(z3) : 0.f;
        accA += p0 * xa0 + p1 * xa1 + p2 * xa2 + p3 * xa3;
        accB += p0 * xb0 + p1 * xb1 + p2 * xb2 + p3 * xb3;
        l += (p0 + p1) + (p2 + p3);
    }

    float inv = 1.f / (l + 1e-16f);
    float a0 = accA.x * inv, a1 = accA.y * inv;
    float a2 = accB.x * inv, a3 = accB.y * inv;
    a0 += __shfl_xor(a0, 16); a0 += __shfl_xor(a0, 32);
    a1 += __shfl_xor(a1, 16); a1 += __shfl_xor(a1, 32);
    a2 += __shfl_xor(a2, 16); a2 += __shfl_xor(a2, 32);
    a3 += __shfl_xor(a3, 16); a3 += __shfl_xor(a3, 32);
    if (lane < 16) {
        float4 bv = bias4[lane];
        float4 o;
        o.x = 0.25f * a0 + bv.x; o.x = (o.x > 0.f) ? o.x : 0.1f * o.x;
        o.y = 0.25f * a1 + bv.y; o.y = (o.y > 0.f) ? o.y : 0.1f * o.y;
        o.z = 0.25f * a2 + bv.z; o.z = (o.z > 0.f) ? o.z : 0.1f * o.z;
        o.w = 0.25f * a3 + bv.w; o.w = (o.w > 0.f) ? o.w : 0.1f * o.w;
        if (hout)
            *reinterpret_cast<float4*>(&hout[(size_t)node * HID + lane * 4]) = o;
        if (hbf) {
            uint2 pk;
            pk.x = pkbf(o.x, o.y);
            pk.y = pkbf(o.z, o.w);
            *reinterpret_cast<uint2*>(&hbf[(size_t)node * 32 + lane * 2]) = pk;
        }
    }
}

// ---------------------------------------------------------------------------
// Pool + BN + FC fused: 196 blocks pool (sorted-run atomics); last block
// (device atomic counter) performs BN over graphs + FC.
// ---------------------------------------------------------------------------
__global__ __launch_bounds__(256) void pool_final_kernel(
    const float* __restrict__ hfin, const int* __restrict__ batch,
    float* __restrict__ pooled,
    const float* __restrict__ gamma, const float* __restrict__ beta,
    const float* __restrict__ fcW, const float* __restrict__ fcb,
    float* __restrict__ out, int* __restrict__ done) {
    int base = blockIdx.x * 256;
    int g = threadIdx.x >> 6, lane = threadIdx.x & 63;
    int lim = min(base + 256, N_NODES);
    int cur = -1;
    float s = 0.f;
    for (int i = base + g; i < lim; i += 4) {
        int b = batch[i];
        if (b != cur) {
            if (cur >= 0) atomicAdd(&pooled[cur * HID + lane], s);
            cur = b; s = 0.f;
        }
        s += hfin[(size_t)i * HID + lane];
    }
    if (cur >= 0) atomicAdd(&pooled[cur * HID + lane], s);

    __threadfence();
    __syncthreads();
    __shared__ int lastS;
    if (threadIdx.x == 0)
        lastS = (atomicAdd(done, 1) == (int)gridDim.x - 1);
    __syncthreads();
    if (!lastS) return;

    // ---- final phase (single block) ----
    __shared__ float P[N_GRAPHS * HID];
    __shared__ float normS[N_GRAPHS * HID];
    __shared__ float meanS[HID], rstdS[HID];
    int t = threadIdx.x;
    for (int i = t; i < N_GRAPHS * HID; i += 256)
        P[i] = __hip_atomic_load(&pooled[i], __ATOMIC_RELAXED, __HIP_MEMORY_SCOPE_AGENT);
    __syncthreads();
    if (t < HID) {
        float s2 = 0.f;
        for (int g2 = 0; g2 < N_GRAPHS; ++g2) s2 += P[g2 * HID + t];
        float mean = s2 / (float)N_GRAPHS;
        float v = 0.f;
        for (int g2 = 0; g2 < N_GRAPHS; ++g2) {
            float dd = P[g2 * HID + t] - mean;
            v += dd * dd;
        }
        v /= (float)N_GRAPHS;
        meanS[t] = mean;
        rstdS[t] = rsqrtf(v + 1e-5f);
    }
    __syncthreads();
    for (int i = t; i < N_GRAPHS * HID; i += 256) {
        int d = i & 63;
        normS[i] = (P[i] - meanS[d]) * rstdS[d] * gamma[d] + beta[d];
    }
    __syncthreads();
    for (int i = t; i < N_GRAPHS * LAT; i += 256) {
        int g2 = i >> 5, lat = i & 31;
        float s2 = fcb[lat];
        for (int d = 0; d < HID; ++d) s2 += normS[g2 * HID + d] * fcW[lat * HID + d];
        out[i] = s2;
    }
}

// ---------------------------------------------------------------------------
extern "C" void kernel_launch(void* const* d_in, const int* in_sizes, int n_in,
                              void* d_out, int out_size, void* d_ws, size_t ws_size,
                              hipStream_t stream) {
    const float* x      = (const float*)d_in[0];
    const int*   ei     = (const int*)d_in[1];
    const int*   batch  = (const int*)d_in[2];
    const float* Wl[3]  = {(const float*)d_in[3], (const float*)d_in[7],  (const float*)d_in[11]};
    const float* Wr[3]  = {(const float*)d_in[4], (const float*)d_in[8],  (const float*)d_in[12]};
    const float* att[3] = {(const float*)d_in[5], (const float*)d_in[9],  (const float*)d_in[13]};
    const float* bia[3] = {(const float*)d_in[6], (const float*)d_in[10], (const float*)d_in[14]};
    const float* gamma  = (const float*)d_in[15];
    const float* beta   = (const float*)d_in[16];
    const float* fcW    = (const float*)d_in[17];
    const float* fcb    = (const float*)d_in[18];
    float* out = (float*)d_out;

    char* p = (char*)d_ws;
    auto alloc = [&](size_t bytes) {
        char* r = p;
        p += (bytes + 255) & ~(size_t)255;
        return r;
    };
    unsigned* xbf   = (unsigned*)alloc((size_t)N_NODES * IN_DIM * 2);   // bf16 x; reused as hfin
    unsigned* xlp   = (unsigned*)alloc((size_t)N_NODES * 256 * 2);
    unsigned* xrp   = (unsigned*)alloc((size_t)N_NODES * 256 * 2);
    unsigned* hbf0  = (unsigned*)alloc((size_t)N_NODES * HID * 2);
    unsigned* hbf1  = (unsigned*)alloc((size_t)N_NODES * HID * 2);
    unsigned short* Bpk0 = (unsigned short*)alloc(32 * 4 * 512 * 2);
    unsigned short* Bpk1 = (unsigned short*)alloc(32 * 2 * 512 * 2);
    unsigned short* Bpk2 = (unsigned short*)alloc(32 * 2 * 512 * 2);
    int*   es      = (int*)alloc((size_t)ES_CAP * 4);
    int*   offs    = (int*)alloc((size_t)N_NODES * 4);
    int*   cnt     = (int*)alloc((size_t)N_NODES * 4);   // true degrees
    int*   sc      = (int*)alloc((size_t)N_NODES * 4);   // scatter cursors
    int*   agg     = (int*)alloc((size_t)SCAN_BLOCKS * 4);
    int*   done    = (int*)alloc(256);
    float* pooled  = (float*)alloc((size_t)N_GRAPHS * HID * 4);
    float* hfin    = (float*)xbf;   // alias: xbf dead after layer-0 GEMM

    const int* srcs = ei;
    const int* dsts = ei + N_EDGES;

    // 1: prep (conv + pack + zeros)
    prep_kernel<<<4096, 256, 0, stream>>>(x, xbf, Wl[0], Wr[0], Wl[1], Wr[1],
                                          Wl[2], Wr[2], Bpk0, Bpk1, Bpk2,
                                          cnt, pooled, done, (uint4*)es);
    // 2-4: counting sort (deg -> lookback scan -> scatter), 4 edges/thread
    int e4 = N_EDGES / 4;
    int eb4 = (e4 + 255) / 256;
    deg_kernel<<<eb4, 256, 0, stream>>>((const int4*)dsts, cnt, e4);
    scan_kernel<<<SCAN_BLOCKS, 256, 0, stream>>>(cnt, offs, sc, agg);
    scatter_kernel<<<eb4, 256, 0, stream>>>((const int4*)srcs, (const int4*)dsts,
                                            offs, sc, es, e4);

    // 5-10: 3 GATv2 layers
    int gb = (N_NODES + 63) / 64;   // 782
    gemm_mfma_kernel<IN_DIM><<<gb, 512, 0, stream>>>((const unsigned short*)xbf, Bpk0, xlp, xrp);
    attn_kernel<<<N_NODES / 4, 256, 0, stream>>>(xlp, xrp, es, offs, cnt,
                                                 (const float4*)att[0],
                                                 (const float4*)bia[0], nullptr, hbf0);
    gemm_mfma_kernel<HID><<<gb, 512, 0, stream>>>((const unsigned short*)hbf0, Bpk1, xlp, xrp);
    attn_kernel<<<N_NODES / 4, 256, 0, stream>>>(xlp, xrp, es, offs, cnt,
                                                 (const float4*)att[1],
                                                 (const float4*)bia[1], nullptr, hbf1);
    gemm_mfma_kernel<HID><<<gb, 512, 0, stream>>>((const unsigned short*)hbf1, Bpk2, xlp, xrp);
    attn_kernel<<<N_NODES / 4, 256, 0, stream>>>(xlp, xrp, es, offs, cnt,
                                                 (const float4*)att[2],
                                                 (const float4*)bia[2], hfin, nullptr);

    // 11: pool + BN + FC (last-block-done)
    pool_final_kernel<<<SCAN_BLOCKS, 256, 0, stream>>>(hfin, batch, pooled,
                                                       gamma, beta, fcW, fcb,
                                                       out, done);
}

// Round 14
// 479.550 us; speedup vs baseline: 1.0432x; 1.0153x over previous
//
#include <hip/hip_runtime.h>
#include <hip/hip_bf16.h>
#include <math.h>
#include <string.h>

#define N_NODES 50000
#define N_EDGES 800000
#define N_GRAPHS 64
#define IN_DIM 128
#define HID 64
#define HEADS 4
#define LAT 32
#define SCAN_BLOCKS ((N_NODES + 255) / 256)   // 196
#define ES_CAP 960000                          // 800k + <=3 pad per node + slack

typedef __attribute__((ext_vector_type(8))) short bf16x8;
typedef __attribute__((ext_vector_type(4))) float floatx4;
typedef __attribute__((ext_vector_type(2))) float f32x2;

__device__ inline unsigned short f2bf(float f) {   // RNE (scalar, prep only)
    unsigned u = __float_as_uint(f);
    return (unsigned short)((u + 0x7fffu + ((u >> 16) & 1u)) >> 16);
}

__device__ inline unsigned pkbf(float x, float y) {   // v_cvt_pk_bf16_f32
    float2 f{x, y};
    __hip_bfloat162 h = __float22bfloat162_rn(f);
    unsigned u;
    memcpy(&u, &h, sizeof(u));
    return u;
}

__device__ inline f32x2 bfpair(unsigned u) {   // packed bf16x2 -> f32x2
    f32x2 r;
    r.x = __uint_as_float(u << 16);
    r.y = __uint_as_float(u & 0xffff0000u);
    return r;
}

// full sum over each 16-lane DPP row via 4 rotational adds (VALU, no DS).
__device__ inline float rowsum16(float x) {
    x += __int_as_float(__builtin_amdgcn_mov_dpp(__float_as_int(x), 0x128, 0xf, 0xf, false));
    x += __int_as_float(__builtin_amdgcn_mov_dpp(__float_as_int(x), 0x124, 0xf, 0xf, false));
    x += __int_as_float(__builtin_amdgcn_mov_dpp(__float_as_int(x), 0x122, 0xf, 0xf, false));
    x += __int_as_float(__builtin_amdgcn_mov_dpp(__float_as_int(x), 0x121, 0xf, 0xf, false));
    return x;
}

// ---------------------------------------------------------------------------
// PREP (1 dispatch): conv + weight pack + zero pooled/done/es + DEG histogram
// (cnt is pre-zeroed by hipMemsetAsync before this dispatch, so the deg
//  block-range can atomically increment concurrently with the other ranges).
// blocks [0,3072): x fp32 -> bf16
// blocks [3072,3584): weight pack (4-tile interleave)
// blocks [3584,3840): zero pooled/done
// blocks [3840,4096): zero es
// blocks [4096,4878): deg histogram, 4 edges/thread
// ---------------------------------------------------------------------------
__global__ __launch_bounds__(256) void prep_kernel(
    const float* __restrict__ x, unsigned* __restrict__ xbf,
    const float* __restrict__ Wl0, const float* __restrict__ Wr0,
    const float* __restrict__ Wl1, const float* __restrict__ Wr1,
    const float* __restrict__ Wl2, const float* __restrict__ Wr2,
    unsigned short* __restrict__ B0, unsigned short* __restrict__ B1,
    unsigned short* __restrict__ B2,
    int* __restrict__ cnt, float* __restrict__ pooled, int* __restrict__ done,
    uint4* __restrict__ es4, const int4* __restrict__ dsts4, int E4) {
    int b = blockIdx.x, t = threadIdx.x;
    if (b < 3072) {
        for (int i = b * 256 + t; i < N_NODES * IN_DIM / 2; i += 3072 * 256) {
            float2 v = reinterpret_cast<const float2*>(x)[i];
            xbf[i] = pkbf(v.x, v.y);
        }
    } else if (b < 3584) {
        int idx = (b - 3072) * 256 + t;   // 0 .. 131071
        const float *Wl, *Wr;
        unsigned short* B;
        int KC, local;
        if (idx < 65536)      { Wl = Wl0; Wr = Wr0; B = B0; KC = 4; local = idx; }
        else if (idx < 98304) { Wl = Wl1; Wr = Wr1; B = B1; KC = 2; local = idx - 65536; }
        else                  { Wl = Wl2; Wr = Wr2; B = B2; KC = 2; local = idx - 98304; }
        int j = local & 7;
        int lane = (local >> 3) & 63;
        int rem = local >> 9;
        int kc = rem % KC;
        int tile = rem / KC;
        int k = kc * 32 + (lane >> 4) * 8 + j;
        int tt = tile & 15;
        int n = (tt >> 2) * 64 + (lane & 15) * 4 + (tt & 3);   // 4-tile interleave
        const float* W = (tile < 16) ? Wl : Wr;
        B[local] = f2bf(W[k * 256 + n]);
    } else if (b < 3840) {
        int idx = (b - 3584) * 256 + t;   // 0 .. 65535
        if (idx < N_GRAPHS * HID) pooled[idx] = 0.f;
        if (idx == 0) *done = 0;
    } else if (b < 4096) {
        int idx = (b - 3840) * 256 + t;   // 0 .. 65535
        for (int i = idx; i < ES_CAP / 4; i += 65536)
            es4[i] = uint4{0, 0, 0, 0};
    } else {
        int i = (b - 4096) * 256 + t;
        if (i < E4) {
            int4 d = dsts4[i];
            atomicAdd(&cnt[d.x], 1);
            atomicAdd(&cnt[d.y], 1);
            atomicAdd(&cnt[d.z], 1);
            atomicAdd(&cnt[d.w], 1);
        }
    }
}

// ---------------------------------------------------------------------------
// Single-kernel exclusive scan of x4-padded degrees, decoupled lookback.
// ---------------------------------------------------------------------------
__global__ __launch_bounds__(256) void scan_kernel(const int* __restrict__ cnt,
                                                   int* __restrict__ offs,
                                                   int* __restrict__ sc,
                                                   int* __restrict__ agg) {
    __shared__ int buf[256];
    int b = blockIdx.x, t = threadIdx.x;
    int i = b * 256 + t;
    int v = (i < N_NODES) ? ((cnt[i] + 3) & ~3) : 0;
    buf[t] = v;
    __syncthreads();
    #pragma unroll
    for (int off = 1; off < 256; off <<= 1) {
        int tmp = (t >= off) ? buf[t - off] : 0;
        __syncthreads();
        buf[t] += tmp;
        __syncthreads();
    }
    int incl = buf[t];
    if (t == 255)
        __hip_atomic_store(&agg[b], buf[255] | 0x40000000,
                           __ATOMIC_RELEASE, __HIP_MEMORY_SCOPE_AGENT);
    int contrib = 0;
    if (t < b) {   // b <= 195 < 256: one predecessor per thread
        int vv;
        do {
            vv = __hip_atomic_load(&agg[t], __ATOMIC_ACQUIRE, __HIP_MEMORY_SCOPE_AGENT);
        } while (vv < 0 || !(vv & 0x40000000));
        contrib = vv & 0x3FFFFFFF;
    }
    __syncthreads();
    buf[t] = contrib;
    __syncthreads();
    for (int off = 128; off; off >>= 1) {
        if (t < off) buf[t] += buf[t + off];
        __syncthreads();
    }
    if (i < N_NODES) {
        offs[i] = buf[0] + incl - v;   // exclusive, 16B-aligned
        sc[i] = 0;
    }
}

// ---------------------------------------------------------------------------
// Fused GEMM0 + SCATTER (independent work, one dispatch):
// blocks [0,782): MFMA GEMM layer-0 (K=128), 64 rows x 512 cols, LDS-staged.
// blocks [782,...): scatter, 8 edges/block-thread-group (512 thr x int4).
// ---------------------------------------------------------------------------
template <int K>
__device__ __forceinline__ void gemm_body(
    const unsigned short* __restrict__ Abf,
    const unsigned short* __restrict__ Bpk,
    unsigned* __restrict__ xlp_u,
    unsigned* __restrict__ xrp_u, int blk, int t) {
    constexpr int KC = K / 32;
    constexpr int CHUNKS = 64 * K / 8;
    __shared__ short As[1024 * 8];            // max K=128 size; K=64 uses half
    int br = blk * 64;

    for (int c = t; c < CHUNKS; c += 512) {
        int rt = c / (KC * 64);
        int rem = c % (KC * 64);
        int kc = rem >> 6;
        int quad = (rem >> 4) & 3, l16 = rem & 15;
        int row = br + rt * 16 + l16;
        if (row >= N_NODES) row = N_NODES - 1;
        *reinterpret_cast<uint4*>(&As[c * 8]) =
            *reinterpret_cast<const uint4*>(&Abf[(size_t)row * K + kc * 32 + quad * 8]);
    }
    __syncthreads();

    int wave = t >> 6, lane = t & 63;
    int quad = lane >> 4, l16 = lane & 15;
    int which = wave >> 2, g = wave & 3;

    bf16x8 afrag[4][KC];
    #pragma unroll
    for (int rt = 0; rt < 4; ++rt)
        #pragma unroll
        for (int kc = 0; kc < KC; ++kc)
            afrag[rt][kc] = *reinterpret_cast<const bf16x8*>(
                &As[(((rt * KC + kc) * 4 + quad) * 16 + l16) * 8]);

    floatx4 acc[4][4];
    #pragma unroll
    for (int rt = 0; rt < 4; ++rt)
        #pragma unroll
        for (int i = 0; i < 4; ++i) acc[rt][i] = floatx4{0.f, 0.f, 0.f, 0.f};

    #pragma unroll
    for (int i = 0; i < 4; ++i) {
        int T = which * 16 + g * 4 + i;
        #pragma unroll
        for (int kc = 0; kc < KC; ++kc) {
            bf16x8 bfr = *reinterpret_cast<const bf16x8*>(
                &Bpk[(size_t)((T * KC + kc) * 64 + lane) * 8]);
            #pragma unroll
            for (int rt = 0; rt < 4; ++rt)
                acc[rt][i] = __builtin_amdgcn_mfma_f32_16x16x32_bf16(
                    afrag[rt][kc], bfr, acc[rt][i], 0, 0, 0);
        }
    }

    unsigned* dst = which ? xrp_u : xlp_u;
    int dcol = g * 32 + l16 * 2;
    #pragma unroll
    for (int rt = 0; rt < 4; ++rt) {
        #pragma unroll
        for (int r = 0; r < 4; ++r) {
            int row = br + rt * 16 + quad * 4 + r;
            if (row >= N_NODES) continue;
            uint2 pk;
            pk.x = pkbf(acc[rt][0][r], acc[rt][1][r]);
            pk.y = pkbf(acc[rt][2][r], acc[rt][3][r]);
            *reinterpret_cast<uint2*>(&dst[(size_t)row * 128 + dcol]) = pk;
        }
    }
}

__global__ __launch_bounds__(512) void gemm0_scatter_kernel(
    const unsigned short* __restrict__ Abf,
    const unsigned short* __restrict__ Bpk,
    unsigned* __restrict__ xlp_u, unsigned* __restrict__ xrp_u,
    const int4* __restrict__ srcs4, const int4* __restrict__ dsts4,
    const int* __restrict__ offs, int* __restrict__ sc,
    int* __restrict__ es, int E4, int GB) {
    if ((int)blockIdx.x < GB) {
        gemm_body<IN_DIM>(Abf, Bpk, xlp_u, xrp_u, blockIdx.x, threadIdx.x);
    } else {
        int i = (blockIdx.x - GB) * 512 + threadIdx.x;
        if (i < E4) {
            int4 s = srcs4[i];
            int4 d = dsts4[i];
            es[offs[d.x] + atomicAdd(&sc[d.x], 1)] = s.x;
            es[offs[d.y] + atomicAdd(&sc[d.y], 1)] = s.y;
            es[offs[d.z] + atomicAdd(&sc[d.z], 1)] = s.z;
            es[offs[d.w] + atomicAdd(&sc[d.w], 1)] = s.w;
        }
    }
}

__global__ __launch_bounds__(512) void gemm_kernel64(
    const unsigned short* __restrict__ Abf,
    const unsigned short* __restrict__ Bpk,
    unsigned* __restrict__ xlp_u, unsigned* __restrict__ xrp_u) {
    gemm_body<HID>(Abf, Bpk, xlp_u, xrp_u, blockIdx.x, threadIdx.x);
}

// ---------------------------------------------------------------------------
// Attention (R8 body — best measured): ONE 64-lane wave per node.
// ---------------------------------------------------------------------------
__global__ __launch_bounds__(256) void attn_kernel(const unsigned* __restrict__ xlp,
                                                   const unsigned* __restrict__ xrp,
                                                   const int* __restrict__ es,
                                                   const int* __restrict__ offs,
                                                   const int* __restrict__ deg,
                                                   const float4* __restrict__ att4,
                                                   const float4* __restrict__ bias4,
                                                   float* __restrict__ hout,
                                                   unsigned* __restrict__ hbf) {
    int node = blockIdx.x * 4 + (threadIdx.x >> 6);
    int lane = threadIdx.x & 63;
    int beg = offs[node];
    int end = beg + deg[node];
    uint2 xr2 = reinterpret_cast<const uint2*>(xrp)[(size_t)node * 64 + lane];
    f32x2 xrA = bfpair(xr2.x), xrB = bfpair(xr2.y);
    float4 at_t = att4[lane];
    f32x2 atA = {at_t.x, at_t.y}, atB = {at_t.z, at_t.w};
    const char* xbase = (const char*)xlp;
    int laneoff = lane << 3;

    float l = 0.f;
    f32x2 accA = {0.f, 0.f}, accB = {0.f, 0.f};

    auto edge_z = [&](uint2 v, f32x2& xa, f32x2& xb) -> float {
        xa = bfpair(v.x);
        xb = bfpair(v.y);
        f32x2 ea = xa + xrA;
        f32x2 eb = xb + xrB;
        ea = __builtin_elementwise_max(ea, ea * 0.2f);
        eb = __builtin_elementwise_max(eb, eb * 0.2f);
        f32x2 zz = ea * atA;
        zz += eb * atB;
        return zz.x + zz.y;
    };
    auto gather = [&](int s) -> uint2 {
        return *reinterpret_cast<const uint2*>(
            xbase + (((size_t)(unsigned)s) << 9) + laneoff);
    };

    for (int cb = beg; cb < end; cb += 4) {
        int4 s4 = *reinterpret_cast<const int4*>(&es[cb]);   // uniform broadcast
        uint2 v0 = gather(s4.x);
        uint2 v1 = gather(s4.y);
        uint2 v2 = gather(s4.z);
        uint2 v3 = gather(s4.w);
        f32x2 xa0, xb0, xa1, xb1, xa2, xb2, xa3, xb3;
        float z0 = rowsum16(edge_z(v0, xa0, xb0));
        float z1 = rowsum16(edge_z(v1, xa1, xb1));
        float z2 = rowsum16(edge_z(v2, xa2, xb2));
        float z3 = rowsum16(edge_z(v3, xa3, xb3));
        float p0 = __expf(z0);                               // cb+0 < end always
        float p1 = (cb + 1 < end) ? __expf(z1) : 0.f;
        float p2 = (cb + 2 < end) ? __expf(z2) : 0.f;
        float p3 = (cb + 3 < end) ? __expf(z3) : 0.f;
        accA += p0 * xa0 + p1 * xa1 + p2 * xa2 + p3 * xa3;
        accB += p0 * xb0 + p1 * xb1 + p2 * xb2 + p3 * xb3;
        l += (p0 + p1) + (p2 + p3);
    }

    float inv = 1.f / (l + 1e-16f);
    float a0 = accA.x * inv, a1 = accA.y * inv;
    float a2 = accB.x * inv, a3 = accB.y * inv;
    a0 += __shfl_xor(a0, 16); a0 += __shfl_xor(a0, 32);
    a1 += __shfl_xor(a1, 16); a1 += __shfl_xor(a1, 32);
    a2 += __shfl_xor(a2, 16); a2 += __shfl_xor(a2, 32);
    a3 += __shfl_xor(a3, 16); a3 += __shfl_xor(a3, 32);
    if (lane < 16) {
        float4 bv = bias4[lane];
        float4 o;
        o.x = 0.25f * a0 + bv.x; o.x = (o.x > 0.f) ? o.x : 0.1f * o.x;
        o.y = 0.25f * a1 + bv.y; o.y = (o.y > 0.f) ? o.y : 0.1f * o.y;
        o.z = 0.25f * a2 + bv.z; o.z = (o.z > 0.f) ? o.z : 0.1f * o.z;
        o.w = 0.25f * a3 + bv.w; o.w = (o.w > 0.f) ? o.w : 0.1f * o.w;
        if (hout)
            *reinterpret_cast<float4*>(&hout[(size_t)node * HID + lane * 4]) = o;
        if (hbf) {
            uint2 pk;
            pk.x = pkbf(o.x, o.y);
            pk.y = pkbf(o.z, o.w);
            *reinterpret_cast<uint2*>(&hbf[(size_t)node * 32 + lane * 2]) = pk;
        }
    }
}

// ---------------------------------------------------------------------------
// Pool + BN + FC fused: 196 blocks pool; last block does BN + FC.
// ---------------------------------------------------------------------------
__global__ __launch_bounds__(256) void pool_final_kernel(
    const float* __restrict__ hfin, const int* __restrict__ batch,
    float* __restrict__ pooled,
    const float* __restrict__ gamma, const float* __restrict__ beta,
    const float* __restrict__ fcW, const float* __restrict__ fcb,
    float* __restrict__ out, int* __restrict__ done) {
    int base = blockIdx.x * 256;
    int g = threadIdx.x >> 6, lane = threadIdx.x & 63;
    int lim = min(base + 256, N_NODES);
    int cur = -1;
    float s = 0.f;
    for (int i = base + g; i < lim; i += 4) {
        int b = batch[i];
        if (b != cur) {
            if (cur >= 0) atomicAdd(&pooled[cur * HID + lane], s);
            cur = b; s = 0.f;
        }
        s += hfin[(size_t)i * HID + lane];
    }
    if (cur >= 0) atomicAdd(&pooled[cur * HID + lane], s);

    __threadfence();
    __syncthreads();
    __shared__ int lastS;
    if (threadIdx.x == 0)
        lastS = (atomicAdd(done, 1) == (int)gridDim.x - 1);
    __syncthreads();
    if (!lastS) return;

    __shared__ float P[N_GRAPHS * HID];
    __shared__ float normS[N_GRAPHS * HID];
    __shared__ float meanS[HID], rstdS[HID];
    int t = threadIdx.x;
    for (int i = t; i < N_GRAPHS * HID; i += 256)
        P[i] = __hip_atomic_load(&pooled[i], __ATOMIC_RELAXED, __HIP_MEMORY_SCOPE_AGENT);
    __syncthreads();
    if (t < HID) {
        float s2 = 0.f;
        for (int g2 = 0; g2 < N_GRAPHS; ++g2) s2 += P[g2 * HID + t];
        float mean = s2 / (float)N_GRAPHS;
        float v = 0.f;
        for (int g2 = 0; g2 < N_GRAPHS; ++g2) {
            float dd = P[g2 * HID + t] - mean;
            v += dd * dd;
        }
        v /= (float)N_GRAPHS;
        meanS[t] = mean;
        rstdS[t] = rsqrtf(v + 1e-5f);
    }
    __syncthreads();
    for (int i = t; i < N_GRAPHS * HID; i += 256) {
        int d = i & 63;
        normS[i] = (P[i] - meanS[d]) * rstdS[d] * gamma[d] + beta[d];
    }
    __syncthreads();
    for (int i = t; i < N_GRAPHS * LAT; i += 256) {
        int g2 = i >> 5, lat = i & 31;
        float s2 = fcb[lat];
        for (int d = 0; d < HID; ++d) s2 += normS[g2 * HID + d] * fcW[lat * HID + d];
        out[i] = s2;
    }
}

// ---------------------------------------------------------------------------
extern "C" void kernel_launch(void* const* d_in, const int* in_sizes, int n_in,
                              void* d_out, int out_size, void* d_ws, size_t ws_size,
                              hipStream_t stream) {
    const float* x      = (const float*)d_in[0];
    const int*   ei     = (const int*)d_in[1];
    const int*   batch  = (const int*)d_in[2];
    const float* Wl[3]  = {(const float*)d_in[3], (const float*)d_in[7],  (const float*)d_in[11]};
    const float* Wr[3]  = {(const float*)d_in[4], (const float*)d_in[8],  (const float*)d_in[12]};
    const float* att[3] = {(const float*)d_in[5], (const float*)d_in[9],  (const float*)d_in[13]};
    const float* bia[3] = {(const float*)d_in[6], (const float*)d_in[10], (const float*)d_in[14]};
    const float* gamma  = (const float*)d_in[15];
    const float* beta   = (const float*)d_in[16];
    const float* fcW    = (const float*)d_in[17];
    const float* fcb    = (const float*)d_in[18];
    float* out = (float*)d_out;

    char* p = (char*)d_ws;
    auto alloc = [&](size_t bytes) {
        char* r = p;
        p += (bytes + 255) & ~(size_t)255;
        return r;
    };
    unsigned* xbf   = (unsigned*)alloc((size_t)N_NODES * IN_DIM * 2);   // bf16 x; reused as hfin
    unsigned* xlp   = (unsigned*)alloc((size_t)N_NODES * 256 * 2);
    unsigned* xrp   = (unsigned*)alloc((size_t)N_NODES * 256 * 2);
    unsigned* hbf0  = (unsigned*)alloc((size_t)N_NODES * HID * 2);
    unsigned* hbf1  = (unsigned*)alloc((size_t)N_NODES * HID * 2);
    unsigned short* Bpk0 = (unsigned short*)alloc(32 * 4 * 512 * 2);
    unsigned short* Bpk1 = (unsigned short*)alloc(32 * 2 * 512 * 2);
    unsigned short* Bpk2 = (unsigned short*)alloc(32 * 2 * 512 * 2);
    int*   es      = (int*)alloc((size_t)ES_CAP * 4);
    int*   offs    = (int*)alloc((size_t)N_NODES * 4);
    int*   cnt     = (int*)alloc((size_t)N_NODES * 4);   // true degrees
    int*   sc      = (int*)alloc((size_t)N_NODES * 4);   // scatter cursors
    int*   agg     = (int*)alloc((size_t)SCAN_BLOCKS * 4);
    int*   done    = (int*)alloc(256);
    float* pooled  = (float*)alloc((size_t)N_GRAPHS * HID * 4);
    float* hfin    = (float*)xbf;   // alias: xbf dead after layer-0 GEMM

    const int* srcs = ei;
    const int* dsts = ei + N_EDGES;
    int e4 = N_EDGES / 4;

    // 0: zero cnt (must precede prep's in-dispatch deg histogram)
    hipMemsetAsync(cnt, 0, (size_t)N_NODES * 4, stream);

    // 1: prep (conv + pack + zeros + deg)
    int degb = (e4 + 255) / 256;   // 782
    prep_kernel<<<4096 + degb, 256, 0, stream>>>(x, xbf, Wl[0], Wr[0], Wl[1], Wr[1],
                                                 Wl[2], Wr[2], Bpk0, Bpk1, Bpk2,
                                                 cnt, pooled, done, (uint4*)es,
                                                 (const int4*)dsts, e4);
    // 2: scan
    scan_kernel<<<SCAN_BLOCKS, 256, 0, stream>>>(cnt, offs, sc, agg);

    // 3: gemm0 (K=128) || scatter  — independent, one dispatch
    int gb = (N_NODES + 63) / 64;     // 782
    int sb = (e4 + 511) / 512;        // 391
    gemm0_scatter_kernel<<<gb + sb, 512, 0, stream>>>(
        (const unsigned short*)xbf, Bpk0, xlp, xrp,
        (const int4*)srcs, (const int4*)dsts, offs, sc, es, e4, gb);

    // 4-8: attn0, layers 1-2, pool+final
    attn_kernel<<<N_NODES / 4, 256, 0, stream>>>(xlp, xrp, es, offs, cnt,
                                                 (const float4*)att[0],
                                                 (const float4*)bia[0], nullptr, hbf0);
    gemm_kernel64<<<gb, 512, 0, stream>>>((const unsigned short*)hbf0, Bpk1, xlp, xrp);
    attn_kernel<<<N_NODES / 4, 256, 0, stream>>>(xlp, xrp, es, offs, cnt,
                                                 (const float4*)att[1],
                                                 (const float4*)bia[1], nullptr, hbf1);
    gemm_kernel64<<<gb, 512, 0, stream>>>((const unsigned short*)hbf1, Bpk2, xlp, xrp);
    attn_kernel<<<N_NODES / 4, 256, 0, stream>>>(xlp, xrp, es, offs, cnt,
                                                 (const float4*)att[2],
                                                 (const float4*)bia[2], hfin, nullptr);

    pool_final_kernel<<<SCAN_BLOCKS, 256, 0, stream>>>(hfin, batch, pooled,
                                                       gamma, beta, fcW, fcb,
                                                       out, done);
}